// Round 8
// baseline (401.140 us; speedup 1.0000x reference)
//
#include <hip/hip_runtime.h>
#include <hip/hip_bf16.h>
#include <math.h>

typedef __bf16 bf16;
typedef bf16 bf16x4 __attribute__((ext_vector_type(4)));
typedef bf16 bf16x8 __attribute__((ext_vector_type(8)));
typedef float f32x4 __attribute__((ext_vector_type(4)));

#define B_ 4
#define S_ 2048
#define HID_ 1024
#define NH_ 16
#define HD_ 64
#define LTS 72   // padded LDS tile stride

// async global->LDS, 16B per lane. LDS dest must be wave-uniform base + lane*16.
__device__ __forceinline__ void async16(const bf16* g, bf16* l) {
  __builtin_amdgcn_global_load_lds(
      (const __attribute__((address_space(1))) void*)g,
      (__attribute__((address_space(3))) void*)l, 16, 0, 0);
}

#define MM16(A, B, C) C = __builtin_amdgcn_mfma_f32_16x16x32_bf16(A, B, C, 0, 0, 0)

// ---------------- fp32 -> bf16 convert
__global__ void cvt_kernel(const float* __restrict__ src, bf16* __restrict__ dst, int n4) {
  int i = blockIdx.x * 256 + threadIdx.x;
  if (i < n4) {
    float4 v = ((const float4*)src)[i];
    bf16x4 o;
    o[0] = (bf16)v.x; o[1] = (bf16)v.y; o[2] = (bf16)v.z; o[3] = (bf16)v.w;
    ((bf16x4*)dst)[i] = o;
  }
}

// K-loop body shared by qkv/proj: named accs, frag loads, 16 MFMAs.
#define DECL_ACC \
  f32x4 a00 = {}, a01 = {}, a02 = {}, a03 = {}; \
  f32x4 a10 = {}, a11 = {}, a12 = {}, a13 = {}; \
  f32x4 a20 = {}, a21 = {}, a22 = {}, a23 = {}; \
  f32x4 a30 = {}, a31 = {}, a32 = {}, a33 = {};

#define KLOOP_FRAGS_MFMA \
    bf16x8 af0 = *(const bf16x8*)(lA + (wm + 0 * 16 + l16) * 32 + quad * 8); \
    bf16x8 af1 = *(const bf16x8*)(lA + (wm + 1 * 16 + l16) * 32 + quad * 8); \
    bf16x8 af2 = *(const bf16x8*)(lA + (wm + 2 * 16 + l16) * 32 + quad * 8); \
    bf16x8 af3 = *(const bf16x8*)(lA + (wm + 3 * 16 + l16) * 32 + quad * 8); \
    bf16x8 bg0 = *(const bf16x8*)(lB + (wn + 0 * 16 + l16) * 32 + quad * 8); \
    bf16x8 bg1 = *(const bf16x8*)(lB + (wn + 1 * 16 + l16) * 32 + quad * 8); \
    bf16x8 bg2 = *(const bf16x8*)(lB + (wn + 2 * 16 + l16) * 32 + quad * 8); \
    bf16x8 bg3 = *(const bf16x8*)(lB + (wn + 3 * 16 + l16) * 32 + quad * 8); \
    MM16(af0, bg0, a00); MM16(af0, bg1, a01); MM16(af0, bg2, a02); MM16(af0, bg3, a03); \
    MM16(af1, bg0, a10); MM16(af1, bg1, a11); MM16(af1, bg2, a12); MM16(af1, bg3, a13); \
    MM16(af2, bg0, a20); MM16(af2, bg1, a21); MM16(af2, bg2, a22); MM16(af2, bg3, a23); \
    MM16(af3, bg0, a30); MM16(af3, bg1, a31); MM16(af3, bg2, a32); MM16(af3, bg3, a33);

// RoPE epilogue per (i, r) — fast trig (range ~2048 rad: __cosf err ~1e-4 << bf16 eps)
#define ROPE_R(i, r, C0, C1, C2, C3) { \
  const int mloc = (i) * 16 + quad * 4 + (r); \
  const float p = (float)pos[mbase + mloc]; \
  const float aa0 = p * invf0, aa1 = p * invf1; \
  const float c0 = __cosf(aa0), sn0 = __sinf(aa0); \
  const float c1 = __cosf(aa1), sn1 = __sinf(aa1); \
  myT[mloc * LTS + l16]      = (bf16)((C0[r] * c0 - C2[r] * sn0) * scl); \
  myT[mloc * LTS + 32 + l16] = (bf16)((C2[r] * c0 + C0[r] * sn0) * scl); \
  myT[mloc * LTS + 16 + l16] = (bf16)((C1[r] * c1 - C3[r] * sn1) * scl); \
  myT[mloc * LTS + 48 + l16] = (bf16)((C3[r] * c1 + C1[r] * sn1) * scl); }
#define ROPE_I(i, C0, C1, C2, C3) \
  ROPE_R(i, 0, C0, C1, C2, C3) ROPE_R(i, 1, C0, C1, C2, C3) \
  ROPE_R(i, 2, C0, C1, C2, C3) ROPE_R(i, 3, C0, C1, C2, C3)

#define VW(i, j, C) { \
  bf16x4 o; o[0] = (bf16)C[0]; o[1] = (bf16)C[1]; o[2] = (bf16)C[2]; o[3] = (bf16)C[3]; \
  *(bf16x4*)(myT + ((j) * 16 + l16) * LTS + (i) * 16 + quad * 4) = o; }

// ---------------- QKV GEMM: Y = Xb @ Wb^T, fused RoPE.
__global__ void qkv_gemm(
    const bf16* __restrict__ X, const bf16* __restrict__ Wq,
    const bf16* __restrict__ Wk, const bf16* __restrict__ Wv,
    const int* __restrict__ pos,
    bf16* __restrict__ Q, bf16* __restrict__ Ko, bf16* __restrict__ Vt) {
  const int z = blockIdx.z;
  const bf16* W = (z == 0) ? Wq : (z == 1) ? Wk : Wv;
  const int m0 = blockIdx.y * 128;
  const int n0 = blockIdx.x * 128;
  __shared__ __align__(16) bf16 lA[128 * 32];
  __shared__ __align__(16) bf16 lB[128 * 32];
  __shared__ __align__(16) bf16 lT[4][64 * LTS];
  const int tid = threadIdx.x;
  const int lane = tid & 63, w = tid >> 6;
  const int wm = (w >> 1) * 64, wn = (w & 1) * 64;
  const int quad = lane >> 4, l16 = lane & 15;

  DECL_ACC

  const int qa = tid, qb = tid + 256;
  const int ra = qa >> 2, ca = (qa & 3) * 8;
  const int rb = qb >> 2, cb = (qb & 3) * 8;

  for (int k0 = 0; k0 < 1024; k0 += 32) {
    async16(X + (size_t)(m0 + ra) * 1024 + k0 + ca, lA + qa * 8);
    async16(X + (size_t)(m0 + rb) * 1024 + k0 + cb, lA + qb * 8);
    async16(W + (size_t)(n0 + ra) * 1024 + k0 + ca, lB + qa * 8);
    async16(W + (size_t)(n0 + rb) * 1024 + k0 + cb, lB + qb * 8);
    __syncthreads();
    KLOOP_FRAGS_MFMA
    __syncthreads();
  }

  const int h = (n0 + wn) >> 6;
  const int mbase = m0 + wm;
  const int b = mbase >> 11, s0 = mbase & 2047;
  bf16* myT = lT[w];

  if (z <= 1) {
    const float scl = (z == 0) ? 0.125f : 1.0f;
    const float invf0 = __expf(-0.28782313662425572f * (float)l16);   // ln(1e4)/32
    const float invf1 = __expf(-0.28782313662425572f * (float)(16 + l16));
    ROPE_I(0, a00, a01, a02, a03)
    ROPE_I(1, a10, a11, a12, a13)
    ROPE_I(2, a20, a21, a22, a23)
    ROPE_I(3, a30, a31, a32, a33)
    asm volatile("s_waitcnt lgkmcnt(0)" ::: "memory");
    bf16* dst = (z == 0) ? Q : Ko;
    const int rr = lane >> 3, cc = lane & 7;
#pragma unroll
    for (int it = 0; it < 8; it++) {
      int mloc = it * 8 + rr;
      bf16x8 v = *(const bf16x8*)(myT + mloc * LTS + cc * 8);
      *(bf16x8*)(dst + (((size_t)b * NH_ + h) * S_ + s0 + mloc) * HD_ + cc * 8) = v;
    }
  } else {
    VW(0, 0, a00) VW(0, 1, a01) VW(0, 2, a02) VW(0, 3, a03)
    VW(1, 0, a10) VW(1, 1, a11) VW(1, 2, a12) VW(1, 3, a13)
    VW(2, 0, a20) VW(2, 1, a21) VW(2, 2, a22) VW(2, 3, a23)
    VW(3, 0, a30) VW(3, 1, a31) VW(3, 2, a32) VW(3, 3, a33)
    asm volatile("s_waitcnt lgkmcnt(0)" ::: "memory");
    const int rr = lane >> 3, cc = lane & 7;
#pragma unroll
    for (int it = 0; it < 8; it++) {
      int d = it * 8 + rr;
      bf16x8 v = *(const bf16x8*)(myT + d * LTS + cc * 8);
      *(bf16x8*)(Vt + (((size_t)b * NH_ + h) * HD_ + d) * S_ + s0 + cc * 8) = v;
    }
  }
}

// ---------------- flash attention v8: 2x q-work per wave to fix the LDS-pipe
// bottleneck. Block = 256 thr / 4 waves covering 128 q-rows; each wave owns
// TWO 16-row halves (A: w*32+l16, B: +16). K/V fragments are read from LDS
// ONCE per iteration and feed both halves' MFMAs (32 MFMA per ~20 b128 reads
// vs 16 before) -- MFMA:LDS ratio doubles, K/V staging per q-row halves.
// P buffer (1 per wave) is reused sequentially: write P_A -> read apA ->
// write P_B -> read apB (per-wave in-order DS makes the WAR safe).
// Staging via global_load_lds (DMA; no wave-issued LDS writes), v4-style
// single __syncthreads per iter. Fixed-shift softmax (v4). Swizzle: chunk c
// of row r at physical c ^ (r&7), applied at the global SOURCE address.
__global__ void __launch_bounds__(256, 3) attn_kernel(
    const bf16* __restrict__ Q, const bf16* __restrict__ K,
    const bf16* __restrict__ Vt, const float* __restrict__ mask,
    bf16* __restrict__ ctx) {
  const int b = blockIdx.y >> 4, h = blockIdx.y & 15;
  const int q0 = blockIdx.x * 128;
  __shared__ __align__(16) bf16 lK[2][64 * 64];  // stages Q rows 0..63; O-out (epilogue)
  __shared__ __align__(16) bf16 lV[2][64 * 64];  // lV[1] stages Q rows 64..127
  __shared__ __align__(16) bf16 lP[4][16 * 64];  // per-wave P, reused A then B
  bf16* lKf = (bf16*)lK;                          // flat 128x64 (epilogue)
  const int tid = threadIdx.x;
  const int lane = tid & 63, w = tid >> 6;
  const int quad = lane >> 4, l16 = lane & 15;

  // staging geometry: rows 0..31 / 32..63 per pair of calls (row&7 == sr&7)
  const int sr = tid >> 3;                // 0..31
  const int scs = (tid & 7) ^ (sr & 7);   // swizzled source chunk

  const size_t headoff = ((size_t)b * NH_ + h) * S_ * HD_;
  {
    const bf16* qsrc = Q + headoff + (size_t)q0 * HD_;
    async16(qsrc + sr * 64 + scs * 8, lK[1] + tid * 8);                  // Q rows 0..31
    async16(qsrc + (sr + 32) * 64 + scs * 8, lK[1] + (tid + 256) * 8);   // 32..63
    async16(qsrc + (size_t)(sr + 64) * 64 + scs * 8, lV[1] + tid * 8);   // 64..95
    async16(qsrc + (size_t)(sr + 96) * 64 + scs * 8, lV[1] + (tid + 256) * 8); // 96..127
    const bf16* ksrc = K + headoff;
    async16(ksrc + sr * 64 + scs * 8, lK[0] + tid * 8);
    async16(ksrc + (sr + 32) * 64 + scs * 8, lK[0] + (tid + 256) * 8);
    const bf16* vbase = Vt + headoff;
    async16(vbase + (size_t)sr * S_ + scs * 8, lV[0] + tid * 8);
    async16(vbase + (size_t)(sr + 32) * S_ + scs * 8, lV[0] + (tid + 256) * 8);
  }

  const float* mrowA = mask + ((size_t)b * S_ + q0 + w * 32 + l16) * S_;
  const float* mrowB = mrowA + (size_t)16 * S_;
  const int sw = l16 & 7;
  const int pq  = (quad ^ sw) * 8;         // physical chunk offset, k-half 0
  const int pq2 = ((quad + 4) ^ sw) * 8;   // k-half 1
  bf16* myP = lP[w];

  const float LOG2E = 1.44269504089f;
  const float MSH = -17.3123404907f;       // -12 * log2e (fixed shift)
#define XMASK(dst, src) { float4 t_ = (src); \
  dst.x = fmaf(t_.x, LOG2E, MSH); dst.y = fmaf(t_.y, LOG2E, MSH); \
  dst.z = fmaf(t_.z, LOG2E, MSH); dst.w = fmaf(t_.w, LOG2E, MSH); }

  // mask tile 0 for both halves (transformed to exp2 domain)
  float4 gA0, gA1, gA2, gA3, gB0, gB1, gB2, gB3;
  {
    const float4* mA = (const float4*)(mrowA);
    XMASK(gA0, mA[quad]); XMASK(gA1, mA[4 + quad]);
    XMASK(gA2, mA[8 + quad]); XMASK(gA3, mA[12 + quad]);
    const float4* mB = (const float4*)(mrowB);
    XMASK(gB0, mB[quad]); XMASK(gB1, mB[4 + quad]);
    XMASK(gB2, mB[8 + quad]); XMASK(gB3, mB[12 + quad]);
  }

  __syncthreads();   // Q, K0, V0 resident
  // hoist Q frags for both halves; rows 0..63 in lK[1], 64..127 in lV[1].
  // (row&7) preserved by staging (offsets 64/96 are 0 mod 8).
  const int rA = w * 32 + l16;
  const bf16* qbA = (rA < 64) ? (lK[1] + rA * 64) : (lV[1] + (rA - 64) * 64);
  const bf16x8 qfA  = *(const bf16x8*)(qbA + pq);
  const bf16x8 qfA2 = *(const bf16x8*)(qbA + pq2);
  const int rB = rA + 16;
  const bf16* qbB = (rB < 64) ? (lK[1] + rB * 64) : (lV[1] + (rB - 64) * 64);
  const bf16x8 qfB  = *(const bf16x8*)(qbB + pq);
  const bf16x8 qfB2 = *(const bf16x8*)(qbB + pq2);
  __syncthreads();   // all waves done reading Q; lK[1]/lV[1] free for staging

  f32x4 oA0 = {}, oA1 = {}, oA2 = {}, oA3 = {};
  f32x4 oB0 = {}, oB1 = {}, oB2 = {}, oB3 = {};
  float laccA = 0.f, laccB = 0.f;

  for (int kt = 0; kt < 32; kt++) {
    const bf16* lKc = lK[kt & 1];
    const bf16* lVc = lV[kt & 1];
    if (kt < 31) {   // stage kt+1 into the other buffer (DMA, drained at barrier)
      bf16* nK = lK[(kt & 1) ^ 1];
      bf16* nV = lV[(kt & 1) ^ 1];
      const int k0n = (kt + 1) * 64;
      const bf16* ksrc = K + headoff + (size_t)k0n * HD_;
      async16(ksrc + sr * 64 + scs * 8, nK + tid * 8);
      async16(ksrc + (sr + 32) * 64 + scs * 8, nK + (tid + 256) * 8);
      const bf16* vbase = Vt + headoff + k0n;
      async16(vbase + (size_t)sr * S_ + scs * 8, nV + tid * 8);
      async16(vbase + (size_t)(sr + 32) * S_ + scs * 8, nV + (tid + 256) * 8);
    }

    // QK^T for both halves; K-frags read ONCE, reused.
    f32x4 sA0 = {}, sA1 = {}, sA2 = {}, sA3 = {};
    f32x4 sB0 = {}, sB1 = {}, sB2 = {}, sB3 = {};
    __builtin_amdgcn_s_setprio(1);
    {
      bf16x8 k0f = *(const bf16x8*)(lKc + (0 * 16 + l16) * 64 + pq);
      bf16x8 k1f = *(const bf16x8*)(lKc + (1 * 16 + l16) * 64 + pq);
      bf16x8 k2f = *(const bf16x8*)(lKc + (2 * 16 + l16) * 64 + pq);
      bf16x8 k3f = *(const bf16x8*)(lKc + (3 * 16 + l16) * 64 + pq);
      MM16(k0f, qfA, sA0); MM16(k1f, qfA, sA1); MM16(k2f, qfA, sA2); MM16(k3f, qfA, sA3);
      MM16(k0f, qfB, sB0); MM16(k1f, qfB, sB1); MM16(k2f, qfB, sB2); MM16(k3f, qfB, sB3);
    }
    {
      bf16x8 k0f = *(const bf16x8*)(lKc + (0 * 16 + l16) * 64 + pq2);
      bf16x8 k1f = *(const bf16x8*)(lKc + (1 * 16 + l16) * 64 + pq2);
      bf16x8 k2f = *(const bf16x8*)(lKc + (2 * 16 + l16) * 64 + pq2);
      bf16x8 k3f = *(const bf16x8*)(lKc + (3 * 16 + l16) * 64 + pq2);
      MM16(k0f, qfA2, sA0); MM16(k1f, qfA2, sA1); MM16(k2f, qfA2, sA2); MM16(k3f, qfA2, sA3);
      MM16(k0f, qfB2, sB0); MM16(k1f, qfB2, sB1); MM16(k2f, qfB2, sB2); MM16(k3f, qfB2, sB3);
    }
    __builtin_amdgcn_s_setprio(0);

    const int swz = 8 * sw;
    // softmax A (fixed shift) + P_A store + apA reads
    bf16x8 apA, apA2;
    {
      float p00 = __builtin_amdgcn_exp2f(fmaf(sA0[0], LOG2E, gA0.x));
      float p01 = __builtin_amdgcn_exp2f(fmaf(sA0[1], LOG2E, gA0.y));
      float p02 = __builtin_amdgcn_exp2f(fmaf(sA0[2], LOG2E, gA0.z));
      float p03 = __builtin_amdgcn_exp2f(fmaf(sA0[3], LOG2E, gA0.w));
      float p10 = __builtin_amdgcn_exp2f(fmaf(sA1[0], LOG2E, gA1.x));
      float p11 = __builtin_amdgcn_exp2f(fmaf(sA1[1], LOG2E, gA1.y));
      float p12 = __builtin_amdgcn_exp2f(fmaf(sA1[2], LOG2E, gA1.z));
      float p13 = __builtin_amdgcn_exp2f(fmaf(sA1[3], LOG2E, gA1.w));
      float p20 = __builtin_amdgcn_exp2f(fmaf(sA2[0], LOG2E, gA2.x));
      float p21 = __builtin_amdgcn_exp2f(fmaf(sA2[1], LOG2E, gA2.y));
      float p22 = __builtin_amdgcn_exp2f(fmaf(sA2[2], LOG2E, gA2.z));
      float p23 = __builtin_amdgcn_exp2f(fmaf(sA2[3], LOG2E, gA2.w));
      float p30 = __builtin_amdgcn_exp2f(fmaf(sA3[0], LOG2E, gA3.x));
      float p31 = __builtin_amdgcn_exp2f(fmaf(sA3[1], LOG2E, gA3.y));
      float p32 = __builtin_amdgcn_exp2f(fmaf(sA3[2], LOG2E, gA3.z));
      float p33 = __builtin_amdgcn_exp2f(fmaf(sA3[3], LOG2E, gA3.w));
      bf16x4 pk;
      pk[0] = (bf16)p00; pk[1] = (bf16)p01; pk[2] = (bf16)p02; pk[3] = (bf16)p03;
      *(bf16x4*)(myP + l16 * 64 + ((0 * 16 + quad * 4) ^ swz)) = pk;
      pk[0] = (bf16)p10; pk[1] = (bf16)p11; pk[2] = (bf16)p12; pk[3] = (bf16)p13;
      *(bf16x4*)(myP + l16 * 64 + ((1 * 16 + quad * 4) ^ swz)) = pk;
      pk[0] = (bf16)p20; pk[1] = (bf16)p21; pk[2] = (bf16)p22; pk[3] = (bf16)p23;
      *(bf16x4*)(myP + l16 * 64 + ((2 * 16 + quad * 4) ^ swz)) = pk;
      pk[0] = (bf16)p30; pk[1] = (bf16)p31; pk[2] = (bf16)p32; pk[3] = (bf16)p33;
      *(bf16x4*)(myP + l16 * 64 + ((3 * 16 + quad * 4) ^ swz)) = pk;
      laccA += (((p00 + p01) + (p02 + p03)) + ((p10 + p11) + (p12 + p13)))
             + (((p20 + p21) + (p22 + p23)) + ((p30 + p31) + (p32 + p33)));
      apA  = *(const bf16x8*)(myP + l16 * 64 + pq);    // in-order DS: sees P_A
      apA2 = *(const bf16x8*)(myP + l16 * 64 + pq2);
    }
    // softmax B + P_B store (overwrites P_A AFTER apA reads -- in-order) + apB
    bf16x8 apB, apB2;
    {
      float p00 = __builtin_amdgcn_exp2f(fmaf(sB0[0], LOG2E, gB0.x));
      float p01 = __builtin_amdgcn_exp2f(fmaf(sB0[1], LOG2E, gB0.y));
      float p02 = __builtin_amdgcn_exp2f(fmaf(sB0[2], LOG2E, gB0.z));
      float p03 = __builtin_amdgcn_exp2f(fmaf(sB0[3], LOG2E, gB0.w));
      float p10 = __builtin_amdgcn_exp2f(fmaf(sB1[0], LOG2E, gB1.x));
      float p11 = __builtin_amdgcn_exp2f(fmaf(sB1[1], LOG2E, gB1.y));
      float p12 = __builtin_amdgcn_exp2f(fmaf(sB1[2], LOG2E, gB1.z));
      float p13 = __builtin_amdgcn_exp2f(fmaf(sB1[3], LOG2E, gB1.w));
      float p20 = __builtin_amdgcn_exp2f(fmaf(sB2[0], LOG2E, gB2.x));
      float p21 = __builtin_amdgcn_exp2f(fmaf(sB2[1], LOG2E, gB2.y));
      float p22 = __builtin_amdgcn_exp2f(fmaf(sB2[2], LOG2E, gB2.z));
      float p23 = __builtin_amdgcn_exp2f(fmaf(sB2[3], LOG2E, gB2.w));
      float p30 = __builtin_amdgcn_exp2f(fmaf(sB3[0], LOG2E, gB3.x));
      float p31 = __builtin_amdgcn_exp2f(fmaf(sB3[1], LOG2E, gB3.y));
      float p32 = __builtin_amdgcn_exp2f(fmaf(sB3[2], LOG2E, gB3.z));
      float p33 = __builtin_amdgcn_exp2f(fmaf(sB3[3], LOG2E, gB3.w));
      bf16x4 pk;
      pk[0] = (bf16)p00; pk[1] = (bf16)p01; pk[2] = (bf16)p02; pk[3] = (bf16)p03;
      *(bf16x4*)(myP + l16 * 64 + ((0 * 16 + quad * 4) ^ swz)) = pk;
      pk[0] = (bf16)p10; pk[1] = (bf16)p11; pk[2] = (bf16)p12; pk[3] = (bf16)p13;
      *(bf16x4*)(myP + l16 * 64 + ((1 * 16 + quad * 4) ^ swz)) = pk;
      pk[0] = (bf16)p20; pk[1] = (bf16)p21; pk[2] = (bf16)p22; pk[3] = (bf16)p23;
      *(bf16x4*)(myP + l16 * 64 + ((2 * 16 + quad * 4) ^ swz)) = pk;
      pk[0] = (bf16)p30; pk[1] = (bf16)p31; pk[2] = (bf16)p32; pk[3] = (bf16)p33;
      *(bf16x4*)(myP + l16 * 64 + ((3 * 16 + quad * 4) ^ swz)) = pk;
      laccB += (((p00 + p01) + (p02 + p03)) + ((p10 + p11) + (p12 + p13)))
             + (((p20 + p21) + (p22 + p23)) + ((p30 + p31) + (p32 + p33)));
      apB  = *(const bf16x8*)(myP + l16 * 64 + pq);
      apB2 = *(const bf16x8*)(myP + l16 * 64 + pq2);
    }

    // PV for both halves; V-frags read ONCE, reused.
    __builtin_amdgcn_s_setprio(1);
    {
      bf16x8 v0 = *(const bf16x8*)(lVc + (0 * 16 + l16) * 64 + pq);
      bf16x8 v1 = *(const bf16x8*)(lVc + (1 * 16 + l16) * 64 + pq);
      bf16x8 v2 = *(const bf16x8*)(lVc + (2 * 16 + l16) * 64 + pq);
      bf16x8 v3 = *(const bf16x8*)(lVc + (3 * 16 + l16) * 64 + pq);
      MM16(apA, v0, oA0); MM16(apA, v1, oA1); MM16(apA, v2, oA2); MM16(apA, v3, oA3);
      MM16(apB, v0, oB0); MM16(apB, v1, oB1); MM16(apB, v2, oB2); MM16(apB, v3, oB3);
    }
    {
      bf16x8 v0 = *(const bf16x8*)(lVc + (0 * 16 + l16) * 64 + pq2);
      bf16x8 v1 = *(const bf16x8*)(lVc + (1 * 16 + l16) * 64 + pq2);
      bf16x8 v2 = *(const bf16x8*)(lVc + (2 * 16 + l16) * 64 + pq2);
      bf16x8 v3 = *(const bf16x8*)(lVc + (3 * 16 + l16) * 64 + pq2);
      MM16(apA2, v0, oA0); MM16(apA2, v1, oA1); MM16(apA2, v2, oA2); MM16(apA2, v3, oA3);
      MM16(apB2, v0, oB0); MM16(apB2, v1, oB1); MM16(apB2, v2, oB2); MM16(apB2, v3, oB3);
    }
    __builtin_amdgcn_s_setprio(0);

    // next mask tiles (g regs dead after softmax; consumed after next barrier)
    if (kt < 31) {
      const float4* mA = (const float4*)(mrowA + (kt + 1) * 64);
      XMASK(gA0, mA[quad]); XMASK(gA1, mA[4 + quad]);
      XMASK(gA2, mA[8 + quad]); XMASK(gA3, mA[12 + quad]);
      const float4* mB = (const float4*)(mrowB + (kt + 1) * 64);
      XMASK(gB0, mB[quad]); XMASK(gB1, mB[4 + quad]);
      XMASK(gB2, mB[8 + quad]); XMASK(gB3, mB[12 + quad]);
    }

    __syncthreads();   // drains DMA staging (vmcnt) + all DS reads (lgkm)
  }

  // epilogue: per-half row-sum reduce, normalize, store via lKf (128x64)
  float lrA = laccA, lrB = laccB;
  lrA += __shfl_xor(lrA, 16); lrA += __shfl_xor(lrA, 32);
  lrB += __shfl_xor(lrB, 16); lrB += __shfl_xor(lrB, 32);
  f32x4 lvA, lvB;
  lvA[0] = __shfl(lrA, quad * 4 + 0); lvB[0] = __shfl(lrB, quad * 4 + 0);
  lvA[1] = __shfl(lrA, quad * 4 + 1); lvB[1] = __shfl(lrB, quad * 4 + 1);
  lvA[2] = __shfl(lrA, quad * 4 + 2); lvB[2] = __shfl(lrB, quad * 4 + 2);
  lvA[3] = __shfl(lrA, quad * 4 + 3); lvB[3] = __shfl(lrB, quad * 4 + 3);
#pragma unroll
  for (int r = 0; r < 4; r++) {
    const float ivA = 1.0f / lvA[r];
    const int sA = w * 32 + quad * 4 + r;
    lKf[sA * 64 + l16]      = (bf16)(oA0[r] * ivA);
    lKf[sA * 64 + 16 + l16] = (bf16)(oA1[r] * ivA);
    lKf[sA * 64 + 32 + l16] = (bf16)(oA2[r] * ivA);
    lKf[sA * 64 + 48 + l16] = (bf16)(oA3[r] * ivA);
    const float ivB = 1.0f / lvB[r];
    const int sB = sA + 16;
    lKf[sB * 64 + l16]      = (bf16)(oB0[r] * ivB);
    lKf[sB * 64 + 16 + l16] = (bf16)(oB1[r] * ivB);
    lKf[sB * 64 + 32 + l16] = (bf16)(oB2[r] * ivB);
    lKf[sB * 64 + 48 + l16] = (bf16)(oB3[r] * ivB);
  }
  __syncthreads();
  {
    const int rr = tid >> 3, cc = tid & 7;   // rr 0..31
#pragma unroll
    for (int it = 0; it < 4; it++) {
      int sloc = it * 32 + rr;
      bf16x8 v = *(const bf16x8*)(lKf + sloc * 64 + cc * 8);
      *(bf16x8*)(ctx + ((size_t)b * S_ + q0 + sloc) * HID_ + h * HD_ + cc * 8) = v;
    }
  }
}

#define PW(i, j, C) { \
  float* po = out + (size_t)(m0 + wm + (i) * 16 + quad * 4) * 1024 + n0 + wn + (j) * 16 + l16; \
  po[0] = C[0]; po[1024] = C[1]; po[2048] = C[2]; po[3072] = C[3]; }

// ---------------- output projection: out(fp32) = ctx @ Wo^T
__global__ void proj_gemm(
    const bf16* __restrict__ A, const bf16* __restrict__ Wo, float* __restrict__ out) {
  const int m0 = blockIdx.y * 128;
  const int n0 = blockIdx.x * 128;
  __shared__ __align__(16) bf16 lA[128 * 32];
  __shared__ __align__(16) bf16 lB[128 * 32];
  const int tid = threadIdx.x;
  const int lane = tid & 63, w = tid >> 6;
  const int wm = (w >> 1) * 64, wn = (w & 1) * 64;
  const int quad = lane >> 4, l16 = lane & 15;

  DECL_ACC
  const int qa = tid, qb = tid + 256;
  const int ra = qa >> 2, ca = (qa & 3) * 8;
  const int rb = qb >> 2, cb = (qb & 3) * 8;

  for (int k0 = 0; k0 < 1024; k0 += 32) {
    async16(A + (size_t)(m0 + ra) * 1024 + k0 + ca, lA + qa * 8);
    async16(A + (size_t)(m0 + rb) * 1024 + k0 + cb, lA + qb * 8);
    async16(Wo + (size_t)(n0 + ra) * 1024 + k0 + ca, lB + qa * 8);
    async16(Wo + (size_t)(n0 + rb) * 1024 + k0 + cb, lB + qb * 8);
    __syncthreads();
    KLOOP_FRAGS_MFMA
    __syncthreads();
  }
  PW(0, 0, a00) PW(0, 1, a01) PW(0, 2, a02) PW(0, 3, a03)
  PW(1, 0, a10) PW(1, 1, a11) PW(1, 2, a12) PW(1, 3, a13)
  PW(2, 0, a20) PW(2, 1, a21) PW(2, 2, a22) PW(2, 3, a23)
  PW(3, 0, a30) PW(3, 1, a31) PW(3, 2, a32) PW(3, 3, a33)
}

__global__ void sentinel_kernel(float* out, int n, float val) {
  int i = blockIdx.x * 256 + threadIdx.x;
  if (i < n) out[i] = val;
}

extern "C" void kernel_launch(void* const* d_in, const int* in_sizes, int n_in,
                              void* d_out, int out_size, void* d_ws, size_t ws_size,
                              hipStream_t stream) {
  const float* X    = (const float*)d_in[0];
  const float* mask = (const float*)d_in[1];
  const int*   pos  = (const int*)d_in[2];
  const float* Wq   = (const float*)d_in[3];
  const float* Wk   = (const float*)d_in[4];
  const float* Wv   = (const float*)d_in[5];
  const float* Wo   = (const float*)d_in[6];
  float* out = (float*)d_out;

  char* ws = (char*)d_ws;
  const size_t SZ = (size_t)B_ * NH_ * S_ * HD_ * sizeof(bf16);  // 16 MiB
  if (ws_size < 3 * SZ) {
    sentinel_kernel<<<(out_size + 255) / 256, 256, 0, stream>>>(
        out, out_size, (float)(ws_size >> 20));
    return;
  }

  // ws layout (48 MiB): [0,16M) Xb then ctx; [16M,32M) Q; [32M,48M) Vt then Wob.
  bf16* Xb  = (bf16*)(ws);
  bf16* ctx = (bf16*)(ws);
  bf16* Q   = (bf16*)(ws + SZ);
  bf16* Vt  = (bf16*)(ws + 2 * SZ);
  bf16* Wob = (bf16*)(ws + 2 * SZ);
  // d_out hosts bf16 K [0,16M) and Wq/Wk/Wv bf16 [16M,22M) until proj overwrites.
  bf16* Kb  = (bf16*)d_out;
  bf16* Wqb = (bf16*)((char*)d_out + SZ);
  bf16* Wkb = Wqb + 1024 * 1024;
  bf16* Wvb = Wkb + 1024 * 1024;

  const int nX4 = (B_ * S_ * HID_) / 4;
  const int nW4 = (HID_ * HID_) / 4;
  cvt_kernel<<<(nX4 + 255) / 256, 256, 0, stream>>>(X, Xb, nX4);
  cvt_kernel<<<(nW4 + 255) / 256, 256, 0, stream>>>(Wq, Wqb, nW4);
  cvt_kernel<<<(nW4 + 255) / 256, 256, 0, stream>>>(Wk, Wkb, nW4);
  cvt_kernel<<<(nW4 + 255) / 256, 256, 0, stream>>>(Wv, Wvb, nW4);

  qkv_gemm<<<dim3(8, 64, 3), 256, 0, stream>>>(Xb, Wqb, Wkb, Wvb, pos, Q, Kb, Vt);
  attn_kernel<<<dim3(16, 64), 256, 0, stream>>>(Q, Kb, Vt, mask, ctx);

  cvt_kernel<<<(nW4 + 255) / 256, 256, 0, stream>>>(Wo, Wob, nW4);
  proj_gemm<<<dim3(8, 64), 256, 0, stream>>>(ctx, Wob, out);
}

// Round 9
// 387.441 us; speedup vs baseline: 1.0354x; 1.0354x over previous
//
#include <hip/hip_runtime.h>
#include <hip/hip_bf16.h>
#include <math.h>

typedef __bf16 bf16;
typedef bf16 bf16x4 __attribute__((ext_vector_type(4)));
typedef bf16 bf16x8 __attribute__((ext_vector_type(8)));
typedef float f32x4 __attribute__((ext_vector_type(4)));

#define B_ 4
#define S_ 2048
#define HID_ 1024
#define NH_ 16
#define HD_ 64
#define LTS 72   // padded LDS tile stride

// async global->LDS, 16B per lane. LDS dest must be wave-uniform base + lane*16.
__device__ __forceinline__ void async16(const bf16* g, bf16* l) {
  __builtin_amdgcn_global_load_lds(
      (const __attribute__((address_space(1))) void*)g,
      (__attribute__((address_space(3))) void*)l, 16, 0, 0);
}

#define MM16(A, B, C) C = __builtin_amdgcn_mfma_f32_16x16x32_bf16(A, B, C, 0, 0, 0)

// ---------------- fp32 -> bf16 convert
__global__ void cvt_kernel(const float* __restrict__ src, bf16* __restrict__ dst, int n4) {
  int i = blockIdx.x * 256 + threadIdx.x;
  if (i < n4) {
    float4 v = ((const float4*)src)[i];
    bf16x4 o;
    o[0] = (bf16)v.x; o[1] = (bf16)v.y; o[2] = (bf16)v.z; o[3] = (bf16)v.w;
    ((bf16x4*)dst)[i] = o;
  }
}

// K-loop body shared by qkv/proj: named accs, frag loads, 16 MFMAs.
#define DECL_ACC \
  f32x4 a00 = {}, a01 = {}, a02 = {}, a03 = {}; \
  f32x4 a10 = {}, a11 = {}, a12 = {}, a13 = {}; \
  f32x4 a20 = {}, a21 = {}, a22 = {}, a23 = {}; \
  f32x4 a30 = {}, a31 = {}, a32 = {}, a33 = {};

#define KLOOP_FRAGS_MFMA \
    bf16x8 af0 = *(const bf16x8*)(lA + (wm + 0 * 16 + l16) * 32 + quad * 8); \
    bf16x8 af1 = *(const bf16x8*)(lA + (wm + 1 * 16 + l16) * 32 + quad * 8); \
    bf16x8 af2 = *(const bf16x8*)(lA + (wm + 2 * 16 + l16) * 32 + quad * 8); \
    bf16x8 af3 = *(const bf16x8*)(lA + (wm + 3 * 16 + l16) * 32 + quad * 8); \
    bf16x8 bg0 = *(const bf16x8*)(lB + (wn + 0 * 16 + l16) * 32 + quad * 8); \
    bf16x8 bg1 = *(const bf16x8*)(lB + (wn + 1 * 16 + l16) * 32 + quad * 8); \
    bf16x8 bg2 = *(const bf16x8*)(lB + (wn + 2 * 16 + l16) * 32 + quad * 8); \
    bf16x8 bg3 = *(const bf16x8*)(lB + (wn + 3 * 16 + l16) * 32 + quad * 8); \
    MM16(af0, bg0, a00); MM16(af0, bg1, a01); MM16(af0, bg2, a02); MM16(af0, bg3, a03); \
    MM16(af1, bg0, a10); MM16(af1, bg1, a11); MM16(af1, bg2, a12); MM16(af1, bg3, a13); \
    MM16(af2, bg0, a20); MM16(af2, bg1, a21); MM16(af2, bg2, a22); MM16(af2, bg3, a23); \
    MM16(af3, bg0, a30); MM16(af3, bg1, a31); MM16(af3, bg2, a32); MM16(af3, bg3, a33);

// RoPE epilogue per (i, r) — fast trig (range ~2048 rad: __cosf err ~1e-4 << bf16 eps)
#define ROPE_R(i, r, C0, C1, C2, C3) { \
  const int mloc = (i) * 16 + quad * 4 + (r); \
  const float p = (float)pos[mbase + mloc]; \
  const float aa0 = p * invf0, aa1 = p * invf1; \
  const float c0 = __cosf(aa0), sn0 = __sinf(aa0); \
  const float c1 = __cosf(aa1), sn1 = __sinf(aa1); \
  myT[mloc * LTS + l16]      = (bf16)((C0[r] * c0 - C2[r] * sn0) * scl); \
  myT[mloc * LTS + 32 + l16] = (bf16)((C2[r] * c0 + C0[r] * sn0) * scl); \
  myT[mloc * LTS + 16 + l16] = (bf16)((C1[r] * c1 - C3[r] * sn1) * scl); \
  myT[mloc * LTS + 48 + l16] = (bf16)((C3[r] * c1 + C1[r] * sn1) * scl); }
#define ROPE_I(i, C0, C1, C2, C3) \
  ROPE_R(i, 0, C0, C1, C2, C3) ROPE_R(i, 1, C0, C1, C2, C3) \
  ROPE_R(i, 2, C0, C1, C2, C3) ROPE_R(i, 3, C0, C1, C2, C3)

#define VW(i, j, C) { \
  bf16x4 o; o[0] = (bf16)C[0]; o[1] = (bf16)C[1]; o[2] = (bf16)C[2]; o[3] = (bf16)C[3]; \
  *(bf16x4*)(myT + ((j) * 16 + l16) * LTS + (i) * 16 + quad * 4) = o; }

// ---------------- QKV GEMM: Y = Xb @ Wb^T, fused RoPE.
// v9: (a) lT shrunk to 2 buffers (18.4KB) used in a 2-phase epilogue
// (waves 0,1 -> barrier -> waves 2,3): LDS 53->34.8KB, 3->4 blocks/CU.
// (b) 1D grid 1536 with bijective XCD-chunk swizzle: each XCD owns 8
// contiguous m-rows (2MB of X, L2-resident); decode m-major, z fastest.
__global__ void qkv_gemm(
    const bf16* __restrict__ X, const bf16* __restrict__ Wq,
    const bf16* __restrict__ Wk, const bf16* __restrict__ Wv,
    const int* __restrict__ pos,
    bf16* __restrict__ Q, bf16* __restrict__ Ko, bf16* __restrict__ Vt) {
  // XCD chunk swizzle: hw id f -> orig = (f%8)*192 + f/8 (1536 = 8*192,
  // bijective). XCD k (f%8==k) gets orig in [192k,192k+192) = m_idx in
  // [8k,8k+8). Decode: m-major, then n, z fastest.
  const int f = blockIdx.x;
  const int orig = (f & 7) * 192 + (f >> 3);
  const int m_idx = orig / 24, nz = orig % 24;
  const int z = nz % 3;
  const bf16* W = (z == 0) ? Wq : (z == 1) ? Wk : Wv;
  const int m0 = m_idx * 128;
  const int n0 = (nz / 3) * 128;
  __shared__ __align__(16) bf16 lA[128 * 32];
  __shared__ __align__(16) bf16 lB[128 * 32];
  __shared__ __align__(16) bf16 lT[2][64 * LTS];  // 2-phase epilogue buffer
  const int tid = threadIdx.x;
  const int lane = tid & 63, w = tid >> 6;
  const int wm = (w >> 1) * 64, wn = (w & 1) * 64;
  const int quad = lane >> 4, l16 = lane & 15;

  DECL_ACC

  const int qa = tid, qb = tid + 256;
  const int ra = qa >> 2, ca = (qa & 3) * 8;
  const int rb = qb >> 2, cb = (qb & 3) * 8;

  for (int k0 = 0; k0 < 1024; k0 += 32) {
    async16(X + (size_t)(m0 + ra) * 1024 + k0 + ca, lA + qa * 8);
    async16(X + (size_t)(m0 + rb) * 1024 + k0 + cb, lA + qb * 8);
    async16(W + (size_t)(n0 + ra) * 1024 + k0 + ca, lB + qa * 8);
    async16(W + (size_t)(n0 + rb) * 1024 + k0 + cb, lB + qb * 8);
    __syncthreads();
    KLOOP_FRAGS_MFMA
    __syncthreads();
  }

  const int h = (n0 + wn) >> 6;
  const int mbase = m0 + wm;
  const int b = mbase >> 11, s0 = mbase & 2047;
  bf16* myT = lT[w & 1];

  // epilogue body (uses myT; per-thread state only)
  auto epilogue = [&]() {
    if (z <= 1) {
      const float scl = (z == 0) ? 0.125f : 1.0f;
      const float invf0 = __expf(-0.28782313662425572f * (float)l16);   // ln(1e4)/32
      const float invf1 = __expf(-0.28782313662425572f * (float)(16 + l16));
      ROPE_I(0, a00, a01, a02, a03)
      ROPE_I(1, a10, a11, a12, a13)
      ROPE_I(2, a20, a21, a22, a23)
      ROPE_I(3, a30, a31, a32, a33)
      asm volatile("s_waitcnt lgkmcnt(0)" ::: "memory");
      bf16* dst = (z == 0) ? Q : Ko;
      const int rr = lane >> 3, cc = lane & 7;
#pragma unroll
      for (int it = 0; it < 8; it++) {
        int mloc = it * 8 + rr;
        bf16x8 v = *(const bf16x8*)(myT + mloc * LTS + cc * 8);
        *(bf16x8*)(dst + (((size_t)b * NH_ + h) * S_ + s0 + mloc) * HD_ + cc * 8) = v;
      }
    } else {
      VW(0, 0, a00) VW(0, 1, a01) VW(0, 2, a02) VW(0, 3, a03)
      VW(1, 0, a10) VW(1, 1, a11) VW(1, 2, a12) VW(1, 3, a13)
      VW(2, 0, a20) VW(2, 1, a21) VW(2, 2, a22) VW(2, 3, a23)
      VW(3, 0, a30) VW(3, 1, a31) VW(3, 2, a32) VW(3, 3, a33)
      asm volatile("s_waitcnt lgkmcnt(0)" ::: "memory");
      const int rr = lane >> 3, cc = lane & 7;
#pragma unroll
      for (int it = 0; it < 8; it++) {
        int d = it * 8 + rr;
        bf16x8 v = *(const bf16x8*)(myT + d * LTS + cc * 8);
        *(bf16x8*)(Vt + (((size_t)b * NH_ + h) * HD_ + d) * S_ + s0 + cc * 8) = v;
      }
    }
  };

  // 2-phase: waves 0,1 use lT[0],lT[1]; barrier; waves 2,3 reuse them.
  if (w < 2) epilogue();
  __syncthreads();
  if (w >= 2) epilogue();
}

// ---------------- flash attention v6 (unchanged; 180.5us measured):
// 256 thr / 4 waves / 64 q-rows, T14 async-STAGE split (global->reg->LDS),
// raw s_barrier + lgkmcnt(0) only (no vmcnt drain), fixed-shift softmax.
// Swizzle: chunk c of row r at physical c ^ (r&7), applied at global SOURCE.
__global__ void __launch_bounds__(256, 4) attn_kernel(
    const bf16* __restrict__ Q, const bf16* __restrict__ K,
    const bf16* __restrict__ Vt, const float* __restrict__ mask,
    bf16* __restrict__ ctx) {
  const int b = blockIdx.y >> 4, h = blockIdx.y & 15;
  const int q0 = blockIdx.x * 64;
  __shared__ __align__(16) bf16 lK[2][64 * 64];  // lK[1] also stages Q, then O-out
  __shared__ __align__(16) bf16 lV[2][64 * 64];  // V^T tiles: [d][k]
  __shared__ __align__(16) bf16 lP[4][16 * 64];  // per-wave P: [n(16)][k(64)], swizzled
  const int tid = threadIdx.x;
  const int lane = tid & 63, w = tid >> 6;
  const int quad = lane >> 4, l16 = lane & 15;

  // staging geometry: rows 0..31 (first half) and 32..63 (second), same row&7
  const int sr = tid >> 3;                // 0..31
  const int scs = (tid & 7) ^ (sr & 7);   // swizzled source chunk

  const size_t headoff = ((size_t)b * NH_ + h) * S_ * HD_;
  {
    const bf16* src = Q + headoff + (size_t)q0 * HD_;
    async16(src + sr * 64 + scs * 8, lK[1] + tid * 8);
    async16(src + (sr + 32) * 64 + scs * 8, lK[1] + (tid + 256) * 8);
    const bf16* ksrc = K + headoff;
    async16(ksrc + sr * 64 + scs * 8, lK[0] + tid * 8);
    async16(ksrc + (sr + 32) * 64 + scs * 8, lK[0] + (tid + 256) * 8);
    const bf16* vbase = Vt + headoff;
    async16(vbase + (size_t)sr * S_ + scs * 8, lV[0] + tid * 8);
    async16(vbase + (size_t)(sr + 32) * S_ + scs * 8, lV[0] + (tid + 256) * 8);
  }

  const float* mrow = mask + ((size_t)b * S_ + q0 + w * 16 + l16) * S_;  // lane's q-row
  const int sw = l16 & 7;
  const int pq  = (quad ^ sw) * 8;         // physical chunk offset, k-half 0
  const int pq2 = ((quad + 4) ^ sw) * 8;   // k-half 1
  bf16* myP = lP[w];

  const float LOG2E = 1.44269504089f;
  const float MSH = -17.3123404907f;       // -12 * log2e (fixed shift)

  // mask tile 0 raw prefetch (transform applied at use)
  float4 g0, g1, g2, g3;
  {
    const float4* m4 = (const float4*)(mrow);
    g0 = m4[quad]; g1 = m4[4 + quad]; g2 = m4[8 + quad]; g3 = m4[12 + quad];
  }

  __syncthreads();   // Q, K0, V0 resident (one-time full drain)
  const bf16x8 qf  = *(const bf16x8*)(lK[1] + (w * 16 + l16) * 64 + pq);
  const bf16x8 qf2 = *(const bf16x8*)(lK[1] + (w * 16 + l16) * 64 + pq2);
  __syncthreads();   // all waves done reading Q; lK[1] free

  // stage tile 1 into registers (committed at iter 0's B)
  bf16x8 kr0, kr1, vr0, vr1;
  {
    const bf16* ksrc = K + headoff + (size_t)64 * HD_;
    kr0 = *(const bf16x8*)(ksrc + sr * 64 + scs * 8);
    kr1 = *(const bf16x8*)(ksrc + (sr + 32) * 64 + scs * 8);
    const bf16* vsrc = Vt + headoff + 64;
    vr0 = *(const bf16x8*)(vsrc + (size_t)sr * S_ + scs * 8);
    vr1 = *(const bf16x8*)(vsrc + (size_t)(sr + 32) * S_ + scs * 8);
  }

  f32x4 o0 = {}, o1 = {}, o2 = {}, o3 = {};
  float l_acc = 0.f;   // per-lane partial row-sum; cross-lane reduce deferred

  for (int kt = 0; kt < 32; kt++) {
    const bf16* lKc = lK[kt & 1];
    const bf16* lVc = lV[kt & 1];

    // A: QK^T. S^T form: A = K-frags (rows = kv-cols), B = Q-frag.
    f32x4 s0 = {}, s1 = {}, s2 = {}, s3 = {};
    __builtin_amdgcn_s_setprio(1);
    {
      bf16x8 k0f = *(const bf16x8*)(lKc + (0 * 16 + l16) * 64 + pq);
      bf16x8 k1f = *(const bf16x8*)(lKc + (1 * 16 + l16) * 64 + pq);
      bf16x8 k2f = *(const bf16x8*)(lKc + (2 * 16 + l16) * 64 + pq);
      bf16x8 k3f = *(const bf16x8*)(lKc + (3 * 16 + l16) * 64 + pq);
      MM16(k0f, qf, s0); MM16(k1f, qf, s1); MM16(k2f, qf, s2); MM16(k3f, qf, s3);
    }
    {
      bf16x8 k0f = *(const bf16x8*)(lKc + (0 * 16 + l16) * 64 + pq2);
      bf16x8 k1f = *(const bf16x8*)(lKc + (1 * 16 + l16) * 64 + pq2);
      bf16x8 k2f = *(const bf16x8*)(lKc + (2 * 16 + l16) * 64 + pq2);
      bf16x8 k3f = *(const bf16x8*)(lKc + (3 * 16 + l16) * 64 + pq2);
      MM16(k0f, qf2, s0); MM16(k1f, qf2, s1); MM16(k2f, qf2, s2); MM16(k3f, qf2, s3);
    }
    __builtin_amdgcn_s_setprio(0);

    // B: commit reg-staged tile kt+1 to the other buffer (compiler inserts the
    // precise vmcnt wait for kr/vr here -- ~full-iteration cover since issue).
    if (kt < 31) {
      bf16* nK = lK[(kt & 1) ^ 1];
      bf16* nV = lV[(kt & 1) ^ 1];
      *(bf16x8*)(nK + tid * 8) = kr0;
      *(bf16x8*)(nK + (tid + 256) * 8) = kr1;
      *(bf16x8*)(nV + tid * 8) = vr0;
      *(bf16x8*)(nV + (tid + 256) * 8) = vr1;
    }

    // C: issue global->reg loads for tile kt+2 and mask kt+1 (temps).
    if (kt < 30) {
      const bf16* ksrc = K + headoff + (size_t)(kt + 2) * 64 * HD_;
      kr0 = *(const bf16x8*)(ksrc + sr * 64 + scs * 8);
      kr1 = *(const bf16x8*)(ksrc + (sr + 32) * 64 + scs * 8);
      const bf16* vsrc = Vt + headoff + (kt + 2) * 64;
      vr0 = *(const bf16x8*)(vsrc + (size_t)sr * S_ + scs * 8);
      vr1 = *(const bf16x8*)(vsrc + (size_t)(sr + 32) * S_ + scs * 8);
    }
    float4 h0, h1, h2, h3;
    if (kt < 31) {
      const float4* mn = (const float4*)(mrow + (kt + 1) * 64);
      h0 = mn[quad]; h1 = mn[4 + quad]; h2 = mn[8 + quad]; h3 = mn[12 + quad];
    }

    // D: fixed-shift softmax: P = exp2(s*log2e + (m*log2e + MSH)).
    const float fx0 = fmaf(g0.x, LOG2E, MSH), fy0 = fmaf(g0.y, LOG2E, MSH);
    const float fz0 = fmaf(g0.z, LOG2E, MSH), fw0 = fmaf(g0.w, LOG2E, MSH);
    const float fx1 = fmaf(g1.x, LOG2E, MSH), fy1 = fmaf(g1.y, LOG2E, MSH);
    const float fz1 = fmaf(g1.z, LOG2E, MSH), fw1 = fmaf(g1.w, LOG2E, MSH);
    const float fx2 = fmaf(g2.x, LOG2E, MSH), fy2 = fmaf(g2.y, LOG2E, MSH);
    const float fz2 = fmaf(g2.z, LOG2E, MSH), fw2 = fmaf(g2.w, LOG2E, MSH);
    const float fx3 = fmaf(g3.x, LOG2E, MSH), fy3 = fmaf(g3.y, LOG2E, MSH);
    const float fz3 = fmaf(g3.z, LOG2E, MSH), fw3 = fmaf(g3.w, LOG2E, MSH);
    float p00 = __builtin_amdgcn_exp2f(fmaf(s0[0], LOG2E, fx0));
    float p01 = __builtin_amdgcn_exp2f(fmaf(s0[1], LOG2E, fy0));
    float p02 = __builtin_amdgcn_exp2f(fmaf(s0[2], LOG2E, fz0));
    float p03 = __builtin_amdgcn_exp2f(fmaf(s0[3], LOG2E, fw0));
    float p10 = __builtin_amdgcn_exp2f(fmaf(s1[0], LOG2E, fx1));
    float p11 = __builtin_amdgcn_exp2f(fmaf(s1[1], LOG2E, fy1));
    float p12 = __builtin_amdgcn_exp2f(fmaf(s1[2], LOG2E, fz1));
    float p13 = __builtin_amdgcn_exp2f(fmaf(s1[3], LOG2E, fw1));
    float p20 = __builtin_amdgcn_exp2f(fmaf(s2[0], LOG2E, fx2));
    float p21 = __builtin_amdgcn_exp2f(fmaf(s2[1], LOG2E, fy2));
    float p22 = __builtin_amdgcn_exp2f(fmaf(s2[2], LOG2E, fz2));
    float p23 = __builtin_amdgcn_exp2f(fmaf(s2[3], LOG2E, fw2));
    float p30 = __builtin_amdgcn_exp2f(fmaf(s3[0], LOG2E, fx3));
    float p31 = __builtin_amdgcn_exp2f(fmaf(s3[1], LOG2E, fy3));
    float p32 = __builtin_amdgcn_exp2f(fmaf(s3[2], LOG2E, fz3));
    float p33 = __builtin_amdgcn_exp2f(fmaf(s3[3], LOG2E, fw3));

    {  // swizzled P stores: element (n=l16, k) at n*64 + (k ^ 8*sw)
      const int swz = 8 * sw;
      bf16x4 pk;
      pk[0] = (bf16)p00; pk[1] = (bf16)p01; pk[2] = (bf16)p02; pk[3] = (bf16)p03;
      *(bf16x4*)(myP + l16 * 64 + ((0 * 16 + quad * 4) ^ swz)) = pk;
      pk[0] = (bf16)p10; pk[1] = (bf16)p11; pk[2] = (bf16)p12; pk[3] = (bf16)p13;
      *(bf16x4*)(myP + l16 * 64 + ((1 * 16 + quad * 4) ^ swz)) = pk;
      pk[0] = (bf16)p20; pk[1] = (bf16)p21; pk[2] = (bf16)p22; pk[3] = (bf16)p23;
      *(bf16x4*)(myP + l16 * 64 + ((2 * 16 + quad * 4) ^ swz)) = pk;
      pk[0] = (bf16)p30; pk[1] = (bf16)p31; pk[2] = (bf16)p32; pk[3] = (bf16)p33;
      *(bf16x4*)(myP + l16 * 64 + ((3 * 16 + quad * 4) ^ swz)) = pk;
    }

    l_acc += (((p00 + p01) + (p02 + p03)) + ((p10 + p11) + (p12 + p13)))
           + (((p20 + p21) + (p22 + p23)) + ((p30 + p31) + (p32 + p33)));

    // E: O += P V
    __builtin_amdgcn_s_setprio(1);
    {
      bf16x8 ap = *(const bf16x8*)(myP + l16 * 64 + pq);
      bf16x8 b0 = *(const bf16x8*)(lVc + (0 * 16 + l16) * 64 + pq);
      bf16x8 b1 = *(const bf16x8*)(lVc + (1 * 16 + l16) * 64 + pq);
      bf16x8 b2 = *(const bf16x8*)(lVc + (2 * 16 + l16) * 64 + pq);
      bf16x8 b3 = *(const bf16x8*)(lVc + (3 * 16 + l16) * 64 + pq);
      MM16(ap, b0, o0); MM16(ap, b1, o1); MM16(ap, b2, o2); MM16(ap, b3, o3);
    }
    {
      bf16x8 ap = *(const bf16x8*)(myP + l16 * 64 + pq2);
      bf16x8 b0 = *(const bf16x8*)(lVc + (0 * 16 + l16) * 64 + pq2);
      bf16x8 b1 = *(const bf16x8*)(lVc + (1 * 16 + l16) * 64 + pq2);
      bf16x8 b2 = *(const bf16x8*)(lVc + (2 * 16 + l16) * 64 + pq2);
      bf16x8 b3 = *(const bf16x8*)(lVc + (3 * 16 + l16) * 64 + pq2);
      MM16(ap, b0, o0); MM16(ap, b1, o1); MM16(ap, b2, o2); MM16(ap, b3, o3);
    }
    __builtin_amdgcn_s_setprio(0);

    // carry mask regs for next iteration
    if (kt < 31) { g0 = h0; g1 = h1; g2 = h2; g3 = h3; }

    // F: raw barrier, NO vmem drain. lgkmcnt(0) makes my ds_writes visible
    // and my ds_reads of buf[cur] complete before anyone re-writes it.
    if (kt < 31) {
      asm volatile("s_waitcnt lgkmcnt(0)" ::: "memory");
      __builtin_amdgcn_sched_barrier(0);
      __builtin_amdgcn_s_barrier();
      __builtin_amdgcn_sched_barrier(0);
    }
  }

  // epilogue: reduce row sums, 1/l, normalize, coalesced store via lK[0]
  float l_run = l_acc;
  l_run += __shfl_xor(l_run, 16);
  l_run += __shfl_xor(l_run, 32);
  f32x4 lv;
  lv[0] = __shfl(l_run, quad * 4 + 0);
  lv[1] = __shfl(l_run, quad * 4 + 1);
  lv[2] = __shfl(l_run, quad * 4 + 2);
  lv[3] = __shfl(l_run, quad * 4 + 3);
  bf16* lO = lK[0];
#pragma unroll
  for (int r = 0; r < 4; r++) {
    const float invl = 1.0f / lv[r];
    const int sloc = w * 16 + quad * 4 + r;
    lO[sloc * 64 + l16]      = (bf16)(o0[r] * invl);
    lO[sloc * 64 + 16 + l16] = (bf16)(o1[r] * invl);
    lO[sloc * 64 + 32 + l16] = (bf16)(o2[r] * invl);
    lO[sloc * 64 + 48 + l16] = (bf16)(o3[r] * invl);
  }
  __syncthreads();
  {
    const int rr = tid >> 3, cc = tid & 7;
#pragma unroll
    for (int it = 0; it < 2; it++) {
      int sloc = it * 32 + rr;
      bf16x8 v = *(const bf16x8*)(lO + sloc * 64 + cc * 8);
      *(bf16x8*)(ctx + ((size_t)b * S_ + q0 + sloc) * HID_ + h * HD_ + cc * 8) = v;
    }
  }
}

#define PW(i, j, C) { \
  float* po = out + (size_t)(m0 + wm + (i) * 16 + quad * 4) * 1024 + n0 + wn + (j) * 16 + l16; \
  po[0] = C[0]; po[1024] = C[1]; po[2048] = C[2]; po[3072] = C[3]; }

// ---------------- output projection: out(fp32) = ctx @ Wo^T
// v9: 1D grid 512 with XCD-chunk swizzle (512 = 8*64): XCD k owns m_idx in
// [8k,8k+8) -> ctx tiles (2MB) and Wo (2MB) both L2-resident per XCD.
__global__ void proj_gemm(
    const bf16* __restrict__ A, const bf16* __restrict__ Wo, float* __restrict__ out) {
  const int f = blockIdx.x;
  const int orig = (f & 7) * 64 + (f >> 3);
  const int m0 = (orig >> 3) * 128;
  const int n0 = (orig & 7) * 128;
  __shared__ __align__(16) bf16 lA[128 * 32];
  __shared__ __align__(16) bf16 lB[128 * 32];
  const int tid = threadIdx.x;
  const int lane = tid & 63, w = tid >> 6;
  const int wm = (w >> 1) * 64, wn = (w & 1) * 64;
  const int quad = lane >> 4, l16 = lane & 15;

  DECL_ACC
  const int qa = tid, qb = tid + 256;
  const int ra = qa >> 2, ca = (qa & 3) * 8;
  const int rb = qb >> 2, cb = (qb & 3) * 8;

  for (int k0 = 0; k0 < 1024; k0 += 32) {
    async16(A + (size_t)(m0 + ra) * 1024 + k0 + ca, lA + qa * 8);
    async16(A + (size_t)(m0 + rb) * 1024 + k0 + cb, lA + qb * 8);
    async16(Wo + (size_t)(n0 + ra) * 1024 + k0 + ca, lB + qa * 8);
    async16(Wo + (size_t)(n0 + rb) * 1024 + k0 + cb, lB + qb * 8);
    __syncthreads();
    KLOOP_FRAGS_MFMA
    __syncthreads();
  }
  PW(0, 0, a00) PW(0, 1, a01) PW(0, 2, a02) PW(0, 3, a03)
  PW(1, 0, a10) PW(1, 1, a11) PW(1, 2, a12) PW(1, 3, a13)
  PW(2, 0, a20) PW(2, 1, a21) PW(2, 2, a22) PW(2, 3, a23)
  PW(3, 0, a30) PW(3, 1, a31) PW(3, 2, a32) PW(3, 3, a33)
}

__global__ void sentinel_kernel(float* out, int n, float val) {
  int i = blockIdx.x * 256 + threadIdx.x;
  if (i < n) out[i] = val;
}

extern "C" void kernel_launch(void* const* d_in, const int* in_sizes, int n_in,
                              void* d_out, int out_size, void* d_ws, size_t ws_size,
                              hipStream_t stream) {
  const float* X    = (const float*)d_in[0];
  const float* mask = (const float*)d_in[1];
  const int*   pos  = (const int*)d_in[2];
  const float* Wq   = (const float*)d_in[3];
  const float* Wk   = (const float*)d_in[4];
  const float* Wv   = (const float*)d_in[5];
  const float* Wo   = (const float*)d_in[6];
  float* out = (float*)d_out;

  char* ws = (char*)d_ws;
  const size_t SZ = (size_t)B_ * NH_ * S_ * HD_ * sizeof(bf16);  // 16 MiB
  if (ws_size < 3 * SZ) {
    sentinel_kernel<<<(out_size + 255) / 256, 256, 0, stream>>>(
        out, out_size, (float)(ws_size >> 20));
    return;
  }

  // ws layout (48 MiB): [0,16M) Xb then ctx; [16M,32M) Q; [32M,48M) Vt then Wob.
  bf16* Xb  = (bf16*)(ws);
  bf16* ctx = (bf16*)(ws);
  bf16* Q   = (bf16*)(ws + SZ);
  bf16* Vt  = (bf16*)(ws + 2 * SZ);
  bf16* Wob = (bf16*)(ws + 2 * SZ);
  // d_out hosts bf16 K [0,16M) and Wq/Wk/Wv bf16 [16M,22M) until proj overwrites.
  bf16* Kb  = (bf16*)d_out;
  bf16* Wqb = (bf16*)((char*)d_out + SZ);
  bf16* Wkb = Wqb + 1024 * 1024;
  bf16* Wvb = Wkb + 1024 * 1024;

  const int nX4 = (B_ * S_ * HID_) / 4;
  const int nW4 = (HID_ * HID_) / 4;
  cvt_kernel<<<(nX4 + 255) / 256, 256, 0, stream>>>(X, Xb, nX4);
  cvt_kernel<<<(nW4 + 255) / 256, 256, 0, stream>>>(Wq, Wqb, nW4);
  cvt_kernel<<<(nW4 + 255) / 256, 256, 0, stream>>>(Wk, Wkb, nW4);
  cvt_kernel<<<(nW4 + 255) / 256, 256, 0, stream>>>(Wv, Wvb, nW4);

  qkv_gemm<<<dim3(1536), 256, 0, stream>>>(Xb, Wqb, Wkb, Wvb, pos, Q, Kb, Vt);
  attn_kernel<<<dim3(32, 64), 256, 0, stream>>>(Q, Kb, Vt, mask, ctx);

  cvt_kernel<<<(nW4 + 255) / 256, 256, 0, stream>>>(Wo, Wob, nW4);
  proj_gemm<<<dim3(512), 256, 0, stream>>>(ctx, Wob, out);
}